// Round 16
// baseline (176.082 us; speedup 1.0000x reference)
//
#include <hip/hip_runtime.h>

typedef float v2f __attribute__((ext_vector_type(2)));
typedef float v4f __attribute__((ext_vector_type(4)));

#define N_ROWS 131072
#define DIM    256
#define KP     16
#define NDOM   8
#define NB     32      // bins
#define GG     100     // barycenter grid

#define EB_N   (NDOM*KP*(NB+1))   // 4224 floats
#define BARY_N (KP*GG)            // 1600

#define GRID   1024
#define WAVES  4
#define NWAVE  (GRID*WAVES)       // 4096 waves
#define QUADS  8                  // 32 rows/wave, 4 rows per iteration, exact

// ALL-BUILTIN cross-lane ops. Functional equivalent of permlane{32,16}_swap+add:
//   result[bit clear] = lo[l] + lo[l^m];  result[bit set] = hi[l] + hi[l^m]
// via keep/send select + __shfl_xor (ds_bpermute-based, hazard-safe).
__device__ __forceinline__ v2f swap32_sum(v2f lo, v2f hi, int lane) {
    bool up = (lane & 32) != 0;
    v2f keep = up ? hi : lo;
    v2f send = up ? lo : hi;
    v2f r;
    r[0] = keep[0] + __shfl_xor(send[0], 32);
    r[1] = keep[1] + __shfl_xor(send[1], 32);
    return r;
}
__device__ __forceinline__ v2f swap16_sum(v2f lo, v2f hi, int lane) {
    bool up = (lane & 16) != 0;
    v2f keep = up ? hi : lo;
    v2f send = up ? lo : hi;
    v2f r;
    r[0] = keep[0] + __shfl_xor(send[0], 16);
    r[1] = keep[1] + __shfl_xor(send[1], 16);
    return r;
}
// DPP cross-lane (builtins — compiler handles hazards)
template <int CTRL>
__device__ __forceinline__ float dppf(float x) {
    return __builtin_bit_cast(float, __builtin_amdgcn_update_dpp(
        0, __builtin_bit_cast(int, x), CTRL, 0xF, 0xF, true));
}
template <int CTRL>
__device__ __forceinline__ int dppi(int x) {
    return __builtin_amdgcn_update_dpp(0, x, CTRL, 0xF, 0xF, true);
}
// full 16-lane sum, every lane gets the total (butterfly over lane bits 0..3)
__device__ __forceinline__ float red16(float v) {
    v += dppf<0xB1>(v);    // quad_perm xor1
    v += dppf<0x4E>(v);    // quad_perm xor2
    v += dppf<0x141>(v);   // row_half_mirror
    v += dppf<0x140>(v);   // row_mirror
    return v;
}
__device__ __forceinline__ void wave_fence() {
    asm volatile("s_waitcnt lgkmcnt(0)" ::: "memory");
    __builtin_amdgcn_sched_barrier(0);  // rule #18
}

// plain v2f arithmetic: compiler emits v_pk_fma_f32 and schedules freely
__device__ __forceinline__ void proj_row(v4f x, const v2f wTo[4][8], v2f P[8]) {
#pragma unroll
    for (int q = 0; q < 8; ++q) P[q] = (v2f){0.f, 0.f};
#pragma unroll
    for (int j = 0; j < 4; ++j) {
        v2f xj = {x[j], x[j]};
#pragma unroll
        for (int q = 0; q < 8; ++q) P[q] += xj * wTo[j][q];
    }
}

// P[8] per-lane partials -> xm for this lane's k = 8*b5+4*b4+(lane&3)
__device__ __forceinline__ float reduce_scatter(v2f P[8], int lane) {
    v2f Q[4];
#pragma unroll
    for (int r = 0; r < 4; ++r)
        Q[r] = swap32_sum(P[r], P[r+4], lane);
    v2f S0 = swap16_sum(Q[0], Q[2], lane);
    v2f S1 = swap16_sum(Q[1], Q[3], lane);
    float a = red16(S0[0]), b = red16(S0[1]);
    float c = red16(S1[0]), d = red16(S1[1]);
    float lo = (lane & 1) ? b : a;
    float hi = (lane & 1) ? d : c;
    return (lane & 2) ? hi : lo;
}

// count-searchsorted + CDF interp + barycenter inverse-CDF -> coeff = xm - z
__device__ __forceinline__ float quantile_map(float xm, const float* ebRow,
                                              const float* cfRow, const float* bqk,
                                              const float e[8]) {
    int cnt = (e[0] <= xm) + (e[1] <= xm) + (e[2] <= xm) + (e[3] <= xm)
            + (e[4] <= xm) + (e[5] <= xm) + (e[6] <= xm) + (e[7] <= xm);
    cnt += dppi<0x124>(cnt);   // row_ror:4 — sums ec groups, keeps lane bits 0,1
    cnt += dppi<0x128>(cnt);   // row_ror:8
    int i0 = min(max(cnt - 1, 0), NB - 1);
    float x0 = ebRow[i0], x1 = ebRow[i0+1];
    float f0 = cfRow[i0], f1 = cfRow[i0+1];
    float t  = fminf(fmaxf(__fdividef(xm - x0, x1 - x0), 0.f), 1.f);
    float u  = f0 + t * (f1 - f0);
    float posv = fminf(fmaxf(u, 0.f), 1.f) * (float)(GG - 1);
    int jj = min((int)posv, GG - 2);
    float ttf = posv - (float)jj;
    float b0 = bqk[jj], b1 = bqk[jj+1];
    return xm - (b0*(1.f - ttf) + b1*ttf);
}

__device__ __forceinline__ void out_row(v4f x, const float* cb, const v2f wTo[4][8],
                                        float* op) {
    v2f c2[8];
#pragma unroll
    for (int q = 0; q < 4; ++q) {
        v4f cv4 = *reinterpret_cast<const v4f*>(&cb[4*q]);   // broadcast read
        c2[2*q]   = (v2f){cv4[0], cv4[1]};
        c2[2*q+1] = (v2f){cv4[2], cv4[3]};
    }
    v4f o4;
#pragma unroll
    for (int j = 0; j < 4; ++j) {
        v2f a = c2[0] * wTo[j][0];
#pragma unroll
        for (int q = 1; q < 8; ++q) a += c2[q] * wTo[j][q];
        o4[j] = x[j] - (a[0] + a[1]);
    }
    *reinterpret_cast<v4f*>(op) = o4;
}

__global__ __launch_bounds__(256, 4)   // proven-safe budget: no scratch
void inb_kernel(const float* __restrict__ X, const int* __restrict__ y,
                const float* __restrict__ wT, const float* __restrict__ be,
                const float* __restrict__ cv, const float* __restrict__ bq,
                float* __restrict__ out)
{
    // LDS: 16896 + 16896 + 6400 + 512 = 40704 B -> 4 blocks/CU (same as R11)
    __shared__ alignas(16) float sEB[EB_N];
    __shared__ alignas(16) float sCDF[EB_N];
    __shared__ alignas(16) float sBARY[BARY_N];
    __shared__ alignas(16) float sCOEFF[WAVES][32];

    const int tid = threadIdx.x;
    for (int i = tid; i < EB_N; i += 256) { sEB[i] = be[i]; sCDF[i] = cv[i]; }
    for (int i = tid; i < BARY_N; i += 256) sBARY[i] = bq[i];
    __syncthreads();

    const int lane = tid & 63;
    const int wid  = tid >> 6;
    const int k  = ((lane & 48) >> 2) | (lane & 3);   // k in lane bits 0,1,4,5
    const int ec = (lane >> 2) & 3;                   // edge-chunk in bits 2,3

    // wT rows 4l..4l+3, all 16 k — feeds projection partials AND output GEMM
    v2f wTo[4][8];
#pragma unroll
    for (int j = 0; j < 4; ++j) {
        const v4f* wrow = reinterpret_cast<const v4f*>(&wT[(4*lane + j)*KP]);
#pragma unroll
        for (int q = 0; q < 4; ++q) {
            v4f v = wrow[q];
            wTo[j][2*q]   = (v2f){v[0], v[1]};
            wTo[j][2*q+1] = (v2f){v[2], v[3]};
        }
    }

    float* cobuf = sCOEFF[wid];
    const float* bqk = &sBARY[k*GG];
    const int gwave = blockIdx.x * WAVES + wid;
    const int xoff  = 4*lane;

    v4f xA = *reinterpret_cast<const v4f*>(&X[(size_t)(gwave          )*DIM + xoff]);
    v4f xB = *reinterpret_cast<const v4f*>(&X[(size_t)(gwave +   NWAVE)*DIM + xoff]);
    v4f xC = *reinterpret_cast<const v4f*>(&X[(size_t)(gwave + 2*NWAVE)*DIM + xoff]);
    v4f xD = *reinterpret_cast<const v4f*>(&X[(size_t)(gwave + 3*NWAVE)*DIM + xoff]);
    int dA = y[gwave], dB = y[gwave + NWAVE], dC = y[gwave + 2*NWAVE], dD = y[gwave + 3*NWAVE];

    for (int it = 0; it < QUADS; ++it) {
        const int rA = gwave + (4*it)*NWAVE;
        const int rB = rA + NWAVE, rC = rA + 2*NWAVE, rD = rA + 3*NWAVE;

        // 4 independent edge-read streams (depend only on prefetched dom)
        const float* ebA = &sEB[(dA*KP + k)*(NB+1)];
        const float* ebB = &sEB[(dB*KP + k)*(NB+1)];
        const float* ebC = &sEB[(dC*KP + k)*(NB+1)];
        const float* ebD = &sEB[(dD*KP + k)*(NB+1)];
        float eA[8], eB[8], eC[8], eD[8];
#pragma unroll
        for (int t = 0; t < 8; ++t) {
            eA[t] = ebA[8*ec + t]; eB[t] = ebB[8*ec + t];
            eC[t] = ebC[8*ec + t]; eD[t] = ebD[8*ec + t];
        }

        // prefetch next quad (clamped; discarded on last iter)
        int nA = rA + 4*NWAVE; if (nA >= N_ROWS) nA = rA;
        int nB = nA + NWAVE;   if (nB >= N_ROWS) nB = rA;
        int nC = nA + 2*NWAVE; if (nC >= N_ROWS) nC = rA;
        int nD = nA + 3*NWAVE; if (nD >= N_ROWS) nD = rA;
        int dA_n = y[nA], dB_n = y[nB], dC_n = y[nC], dD_n = y[nD];
        v4f xA_n = *reinterpret_cast<const v4f*>(&X[(size_t)nA*DIM + xoff]);
        v4f xB_n = *reinterpret_cast<const v4f*>(&X[(size_t)nB*DIM + xoff]);
        v4f xC_n = *reinterpret_cast<const v4f*>(&X[(size_t)nC*DIM + xoff]);
        v4f xD_n = *reinterpret_cast<const v4f*>(&X[(size_t)nD*DIM + xoff]);

        // sub-pair proj+reduce (caps live P registers at 2 rows)
        float xmA, xmB, xmC, xmD;
        {
            v2f PA[8], PB[8];
            proj_row(xA, wTo, PA);
            proj_row(xB, wTo, PB);
            xmA = reduce_scatter(PA, lane);
            xmB = reduce_scatter(PB, lane);
        }
        {
            v2f PC[8], PD[8];
            proj_row(xC, wTo, PC);
            proj_row(xD, wTo, PD);
            xmC = reduce_scatter(PC, lane);
            xmD = reduce_scatter(PD, lane);
        }

        // 4 overlapping quantile chains
        float cA = quantile_map(xmA, ebA, &sCDF[(dA*KP + k)*(NB+1)], bqk, eA);
        float cB = quantile_map(xmB, ebB, &sCDF[(dB*KP + k)*(NB+1)], bqk, eB);
        float cC = quantile_map(xmC, ebC, &sCDF[(dC*KP + k)*(NB+1)], bqk, eC);
        float cD = quantile_map(xmD, ebD, &sCDF[(dD*KP + k)*(NB+1)], bqk, eD);

        // phase 1: A,B — exact R11 write/fence/out pattern
        if (ec < 2) cobuf[ec*16 + k] = (ec == 0) ? cA : cB;
        wave_fence();
        out_row(xA, cobuf,      wTo, &out[(size_t)rA*DIM + xoff]);
        out_row(xB, cobuf + 16, wTo, &out[(size_t)rB*DIM + xoff]);

        // phase 2: C,D — same pattern, reusing the 32-slot buffer
        if (ec < 2) cobuf[ec*16 + k] = (ec == 0) ? cC : cD;
        wave_fence();
        out_row(xC, cobuf,      wTo, &out[(size_t)rC*DIM + xoff]);
        out_row(xD, cobuf + 16, wTo, &out[(size_t)rD*DIM + xoff]);

        xA = xA_n; xB = xB_n; xC = xC_n; xD = xD_n;
        dA = dA_n; dB = dB_n; dC = dC_n; dD = dD_n;
    }
}

extern "C" void kernel_launch(void* const* d_in, const int* in_sizes, int n_in,
                              void* d_out, int out_size, void* d_ws, size_t ws_size,
                              hipStream_t stream) {
    const float* X  = (const float*)d_in[0];
    const int*   y  = (const int*)  d_in[1];
    const float* wT = (const float*)d_in[2];
    const float* be = (const float*)d_in[3];
    const float* cv = (const float*)d_in[4];
    const float* bq = (const float*)d_in[5];
    float* out = (float*)d_out;
    hipLaunchKernelGGL(inb_kernel, dim3(GRID), dim3(256), 0, stream,
                       X, y, wT, be, cv, bq, out);
}

// Round 17
// 77.505 us; speedup vs baseline: 2.2719x; 2.2719x over previous
//
#include <hip/hip_runtime.h>

typedef float v2f __attribute__((ext_vector_type(2)));
typedef float v4f __attribute__((ext_vector_type(4)));

#define N_ROWS 131072
#define DIM    256
#define KP     16
#define NDOM   8
#define NB     32      // bins
#define GG     100     // barycenter grid

#define EB_N   (NDOM*KP*(NB+1))   // 4224 floats
#define BARY_N (KP*GG)            // 1600

#define GRID   2048
#define WAVES  4
#define NWAVE  (GRID*WAVES)       // 8192 waves
#define PAIRS  8                  // 16 rows/wave, 2 rows per iteration, exact

// Hazard-safe cross-lane swap-sums (R16-proven): equivalent of
// permlane{32,16}_swap + add, but via keep/send select + __shfl_xor so the
// compiler sees every instruction (inline-asm permlane corrupted data in
// dense schedules — R13 vs R16 bisect).
__device__ __forceinline__ v2f swap32_sum(v2f lo, v2f hi, int lane) {
    bool up = (lane & 32) != 0;
    v2f keep = up ? hi : lo;
    v2f send = up ? lo : hi;
    v2f r;
    r[0] = keep[0] + __shfl_xor(send[0], 32);
    r[1] = keep[1] + __shfl_xor(send[1], 32);
    return r;
}
__device__ __forceinline__ v2f swap16_sum(v2f lo, v2f hi, int lane) {
    bool up = (lane & 16) != 0;
    v2f keep = up ? hi : lo;
    v2f send = up ? lo : hi;
    v2f r;
    r[0] = keep[0] + __shfl_xor(send[0], 16);
    r[1] = keep[1] + __shfl_xor(send[1], 16);
    return r;
}
// DPP cross-lane (builtins — compiler handles hazards)
template <int CTRL>
__device__ __forceinline__ float dppf(float x) {
    return __builtin_bit_cast(float, __builtin_amdgcn_update_dpp(
        0, __builtin_bit_cast(int, x), CTRL, 0xF, 0xF, true));
}
template <int CTRL>
__device__ __forceinline__ int dppi(int x) {
    return __builtin_amdgcn_update_dpp(0, x, CTRL, 0xF, 0xF, true);
}
// full 16-lane sum, every lane gets the total (butterfly over lane bits 0..3)
__device__ __forceinline__ float red16(float v) {
    v += dppf<0xB1>(v);    // quad_perm xor1
    v += dppf<0x4E>(v);    // quad_perm xor2
    v += dppf<0x141>(v);   // row_half_mirror
    v += dppf<0x140>(v);   // row_mirror
    return v;
}
__device__ __forceinline__ void wave_fence() {
    asm volatile("s_waitcnt lgkmcnt(0)" ::: "memory");
    __builtin_amdgcn_sched_barrier(0);  // rule #18
}

// plain v2f arithmetic: compiler emits v_pk_fma_f32 and schedules freely
__device__ __forceinline__ void proj_row(v4f x, const v2f wTo[4][8], v2f P[8]) {
#pragma unroll
    for (int q = 0; q < 8; ++q) P[q] = (v2f){0.f, 0.f};
#pragma unroll
    for (int j = 0; j < 4; ++j) {
        v2f xj = {x[j], x[j]};
#pragma unroll
        for (int q = 0; q < 8; ++q) P[q] += xj * wTo[j][q];
    }
}

// P[8] per-lane partials -> xm for this lane's k = 8*b5+4*b4+(lane&3)
__device__ __forceinline__ float reduce_scatter(v2f P[8], int lane) {
    v2f Q[4];
#pragma unroll
    for (int r = 0; r < 4; ++r)
        Q[r] = swap32_sum(P[r], P[r+4], lane);
    v2f S0 = swap16_sum(Q[0], Q[2], lane);
    v2f S1 = swap16_sum(Q[1], Q[3], lane);
    float a = red16(S0[0]), b = red16(S0[1]);
    float c = red16(S1[0]), d = red16(S1[1]);
    float lo = (lane & 1) ? b : a;
    float hi = (lane & 1) ? d : c;
    return (lane & 2) ? hi : lo;
}

// count-searchsorted + CDF interp + barycenter inverse-CDF -> coeff = xm - z
// edges from LDS; cdf + bary from global (L1-resident tables, 16.9/6.4 KB)
__device__ __forceinline__ float quantile_map(float xm, const float* ebRow,
                                              const float* cfRow, const float* bqk,
                                              const float e[8]) {
    int cnt = (e[0] <= xm) + (e[1] <= xm) + (e[2] <= xm) + (e[3] <= xm)
            + (e[4] <= xm) + (e[5] <= xm) + (e[6] <= xm) + (e[7] <= xm);
    cnt += dppi<0x124>(cnt);   // row_ror:4 — sums ec groups, keeps lane bits 0,1
    cnt += dppi<0x128>(cnt);   // row_ror:8
    int i0 = min(max(cnt - 1, 0), NB - 1);
    float x0 = ebRow[i0], x1 = ebRow[i0+1];
    float f0 = cfRow[i0], f1 = cfRow[i0+1];
    float t  = fminf(fmaxf(__fdividef(xm - x0, x1 - x0), 0.f), 1.f);
    float u  = f0 + t * (f1 - f0);
    float posv = fminf(fmaxf(u, 0.f), 1.f) * (float)(GG - 1);
    int jj = min((int)posv, GG - 2);
    float ttf = posv - (float)jj;
    float b0 = bqk[jj], b1 = bqk[jj+1];
    return xm - (b0*(1.f - ttf) + b1*ttf);
}

__device__ __forceinline__ void out_row(v4f x, const float* cb, const v2f wTo[4][8],
                                        float* op) {
    v2f c2[8];
#pragma unroll
    for (int q = 0; q < 4; ++q) {
        v4f cv4 = *reinterpret_cast<const v4f*>(&cb[4*q]);   // broadcast read
        c2[2*q]   = (v2f){cv4[0], cv4[1]};
        c2[2*q+1] = (v2f){cv4[2], cv4[3]};
    }
    v4f o4;
#pragma unroll
    for (int j = 0; j < 4; ++j) {
        v2f a = c2[0] * wTo[j][0];
#pragma unroll
        for (int q = 1; q < 8; ++q) a += c2[q] * wTo[j][q];
        o4[j] = x[j] - (a[0] + a[1]);
    }
    *reinterpret_cast<v4f*>(op) = o4;
}

__global__ __launch_bounds__(256, 4)   // proven-safe budget: no scratch
void inb_kernel(const float* __restrict__ X, const int* __restrict__ y,
                const float* __restrict__ wT, const float* __restrict__ be,
                const float* __restrict__ cv, const float* __restrict__ bq,
                float* __restrict__ out)
{
    // LDS diet for 8 blocks/CU: 16896 + 512 = 17408 B <= 20480 (160K/8)
    // -> 32 waves/CU at VGPR<=64 (the actual lever: 4 -> 8 waves/SIMD)
    __shared__ alignas(16) float sEB[EB_N];
    __shared__ alignas(16) float sCOEFF[WAVES][32];

    const int tid = threadIdx.x;
    for (int i = tid; i < EB_N; i += 256) sEB[i] = be[i];
    __syncthreads();

    const int lane = tid & 63;
    const int wid  = tid >> 6;
    const int k  = ((lane & 48) >> 2) | (lane & 3);   // k in lane bits 0,1,4,5
    const int ec = (lane >> 2) & 3;                   // edge-chunk in bits 2,3

    // wT rows 4l..4l+3, all 16 k — feeds projection partials AND output GEMM
    v2f wTo[4][8];
#pragma unroll
    for (int j = 0; j < 4; ++j) {
        const v4f* wrow = reinterpret_cast<const v4f*>(&wT[(4*lane + j)*KP]);
#pragma unroll
        for (int q = 0; q < 4; ++q) {
            v4f v = wrow[q];
            wTo[j][2*q]   = (v2f){v[0], v[1]};
            wTo[j][2*q+1] = (v2f){v[2], v[3]};
        }
    }

    float* cobuf = sCOEFF[wid];
    const float* bqk = bq + k*GG;           // global, L1-resident
    const int gwave = blockIdx.x * WAVES + wid;
    const int xoff  = 4*lane;

    v4f xA = *reinterpret_cast<const v4f*>(&X[(size_t)gwave*DIM + xoff]);
    v4f xB = *reinterpret_cast<const v4f*>(&X[(size_t)(gwave + NWAVE)*DIM + xoff]);
    int dA = y[gwave], dB = y[gwave + NWAVE];

    for (int it = 0; it < PAIRS; ++it) {
        const int rA = gwave + (2*it)*NWAVE;
        const int rB = rA + NWAVE;

        // edge reads first (depend only on prefetched dom)
        const float* ebA = &sEB[(dA*KP + k)*(NB+1)];
        const float* ebB = &sEB[(dB*KP + k)*(NB+1)];
        float eA[8], eB[8];
#pragma unroll
        for (int t = 0; t < 8; ++t) { eA[t] = ebA[8*ec + t]; eB[t] = ebB[8*ec + t]; }

        // prefetch next pair (clamped; unused on last iter)
        int nA = rA + 2*NWAVE; if (nA >= N_ROWS) nA = rA;
        int nB = nA + NWAVE;   if (nB >= N_ROWS) nB = rA;
        int dA_n = y[nA], dB_n = y[nB];
        v4f xA_n = *reinterpret_cast<const v4f*>(&X[(size_t)nA*DIM + xoff]);
        v4f xB_n = *reinterpret_cast<const v4f*>(&X[(size_t)nB*DIM + xoff]);

        v2f PA[8], PB[8];
        proj_row(xA, wTo, PA);
        proj_row(xB, wTo, PB);

        float xmA = reduce_scatter(PA, lane);
        float xmB = reduce_scatter(PB, lane);

        float cA = quantile_map(xmA, ebA, cv + (size_t)(dA*KP + k)*(NB+1), bqk, eA);
        float cB = quantile_map(xmB, ebB, cv + (size_t)(dB*KP + k)*(NB+1), bqk, eB);

        if (ec < 2) cobuf[ec*16 + k] = (ec == 0) ? cA : cB;   // 32 lanes, 32 banks
        wave_fence();

        out_row(xA, cobuf,      wTo, &out[(size_t)rA*DIM + xoff]);
        out_row(xB, cobuf + 16, wTo, &out[(size_t)rB*DIM + xoff]);

        xA = xA_n; xB = xB_n; dA = dA_n; dB = dB_n;
    }
}

extern "C" void kernel_launch(void* const* d_in, const int* in_sizes, int n_in,
                              void* d_out, int out_size, void* d_ws, size_t ws_size,
                              hipStream_t stream) {
    const float* X  = (const float*)d_in[0];
    const int*   y  = (const int*)  d_in[1];
    const float* wT = (const float*)d_in[2];
    const float* be = (const float*)d_in[3];
    const float* cv = (const float*)d_in[4];
    const float* bq = (const float*)d_in[5];
    float* out = (float*)d_out;
    hipLaunchKernelGGL(inb_kernel, dim3(GRID), dim3(256), 0, stream,
                       X, y, wT, be, cv, bq, out);
}